// Round 1
// baseline (69.889 us; speedup 1.0000x reference)
//
#include <hip/hip_runtime.h>

// Problem constants (from reference)
static constexpr int  B_  = 524288;
static constexpr int  K_  = 17;
static constexpr int  BK  = B_ * K_;            // 8912896 (b,k) pairs
static constexpr int  NTH = BK / 4;             // 2228224 threads, 4 pairs each
static constexpr long long OFF_Z   = (long long)BK * 2;  // 17825792 floats (after gt_xy)
static constexpr long long OFF_IDX = OFF_Z + BK;         // 26738688 floats (after gt_loc_z)

// clip bounds
#define MAXXY 504.0f   // (64-1)*8.0
#define MAXZ  3.15f    // (64-1)*0.05

__global__ __launch_bounds__(256)
void kp_gt_kernel(const float4* __restrict__ in4, float* __restrict__ out) {
    int i = blockIdx.x * blockDim.x + threadIdx.x;
    if (i >= NTH) return;

    // 4 pairs = 12 consecutive floats = 3 float4 loads (fully coalesced, 16B/lane)
    const float4 v0 = in4[3LL * i + 0];
    const float4 v1 = in4[3LL * i + 1];
    const float4 v2 = in4[3LL * i + 2];

    const float px[4] = {v0.x, v0.w, v1.z, v2.y};
    const float py[4] = {v0.y, v1.x, v1.w, v2.z};
    const float pz[4] = {v0.z, v1.y, v2.x, v2.w};

    float cx[4], cy[4], cz[4], fx[4], fy[4];
#pragma unroll
    for (int j = 0; j < 4; ++j) {
        cx[j] = fminf(fmaxf(px[j], 0.0f), MAXXY);
        cy[j] = fminf(fmaxf(py[j], 0.0f), MAXXY);
        cz[j] = fminf(fmaxf(pz[j], 0.0f), MAXZ);
        // (cx - 0)/8.0 truncated to int32; *0.125f is bit-exact vs /8.0f,
        // values are non-negative after clip so (int) == astype(int32)
        fx[j] = (float)(int)(cx[j] * 0.125f);
        fy[j] = (float)(int)(cy[j] * 0.125f);
    }

    // batch index b = pair/17 : one magic-mul division + incremental carry
    int p0 = 4 * i;
    int b0 = p0 / 17;
    int r  = p0 - b0 * 17;
    float fb[4];
#pragma unroll
    for (int j = 0; j < 4; ++j) {
        fb[j] = (float)b0;
        if (++r == 17) { r = 0; ++b0; }
    }

    // out[0 .. 2*BK)           : gt_xy     [B,K,2]  (8 floats -> 2x float4)
    float4* oxy = (float4*)out;
    oxy[2LL * i + 0] = make_float4(cx[0], cy[0], cx[1], cy[1]);
    oxy[2LL * i + 1] = make_float4(cx[2], cy[2], cx[3], cy[3]);

    // out[OFF_Z .. OFF_Z+BK)   : gt_loc_z  [B*K]    (4 floats -> 1x float4)
    float4* oz = (float4*)(out + OFF_Z);
    oz[i] = make_float4(cz[0], cz[1], cz[2], cz[3]);

    // out[OFF_IDX .. +3*BK)    : gt_index_z [B*K,3] (12 floats -> 3x float4)
    float4* oi = (float4*)(out + OFF_IDX);
    oi[3LL * i + 0] = make_float4(fb[0], fx[0], fy[0], fb[1]);
    oi[3LL * i + 1] = make_float4(fx[1], fy[1], fb[2], fx[2]);
    oi[3LL * i + 2] = make_float4(fy[2], fb[3], fx[3], fy[3]);
}

extern "C" void kernel_launch(void* const* d_in, const int* in_sizes, int n_in,
                              void* d_out, int out_size, void* d_ws, size_t ws_size,
                              hipStream_t stream) {
    const float4* in4 = (const float4*)d_in[0];
    float* out = (float*)d_out;
    const int block = 256;
    const int grid  = (NTH + block - 1) / block;  // 8704 blocks
    kp_gt_kernel<<<grid, block, 0, stream>>>(in4, out);
}